// Round 3
// baseline (712.493 us; speedup 1.0000x reference)
//
#include <hip/hip_runtime.h>
#include <cstddef>

// B=2, CI=CO=64, NS=16, NPTS=1024
constexpr int P_TOTAL = 32768;   // total points
constexpr int NCH     = 64;
constexpr int PPB     = 32;      // points per block
constexpr int PPW     = 8;       // points per wave (4 waves/block)
constexpr int XPAD    = 68;      // xt row stride (floats), 16B-aligned

// y[o,p] = b[o] + sum_i W[o,i]*x[i,p]*(1 + 0.1*eps[p,o,i])
//
// eps[p] viewed as 1024 float4s: flat q = k*64 + lane -> (o=q>>4, i0=4*(q&15)),
// identical flat layout to W, so contiguous 1KB wave loads pair with Wl[q].
// Register double-buffer: point j+1's 16 loads are issued BEFORE consuming
// point j's registers, so the wait before compute is vmcnt(16), not vmcnt(0) —
// every wave keeps ~16KB outstanding continuously.
__global__ __launch_bounds__(256, 2) void noise_conv_kernel(
    const float* __restrict__ x, const float* __restrict__ W,
    const float* __restrict__ bias, const float* __restrict__ eps,
    float* __restrict__ out)
{
    __shared__ __align__(16) float4 Wl[NCH * NCH / 4];  // 16 KB flat W
    __shared__ __align__(16) float  xt[PPB][XPAD];      // xt[j][i] = x[i, p0+j]

    const int tid  = threadIdx.x;
    const int lane = tid & 63;
    const int wv   = tid >> 6;
    const int p0   = blockIdx.x * PPB;
    const int g    = lane >> 4;     // o = 4k + g
    const int s    = lane & 15;     // i0 = 4s

    const float4* W4 = reinterpret_cast<const float4*>(W);
#pragma unroll
    for (int c = 0; c < 4; ++c) {
        int idx = c * 256 + tid;
        Wl[idx] = W4[idx];
    }
#pragma unroll
    for (int c = 0; c < (PPB * NCH) / 256; ++c) {
        int e = c * 256 + tid;
        int i = e >> 5;
        int j = e & (PPB - 1);
        xt[j][i] = x[i * P_TOTAL + p0 + j];
    }

    const int   o_fin = 4 * s + g;
    const float b_fin = bias[o_fin];

    const int jj0 = wv * PPW;
    const float4* ep_base = reinterpret_cast<const float4*>(eps) + lane;

    // Prime: load point jj0's full eps row (16 coalesced 1KB wave loads).
    float4 e[16];
    {
        const float4* ep4 = ep_base + (size_t)(p0 + jj0) * (NCH * NCH / 4);
#pragma unroll
        for (int k = 0; k < 16; ++k) e[k] = ep4[k * 64];
    }

    __syncthreads();

#pragma unroll
    for (int j = 0; j < PPW; ++j) {
        const int jj = jj0 + j;
        const int p  = p0 + jj;

        // Prefetch next point BEFORE consuming e — keeps vmcnt at 16, not 0.
        float4 en[16];
        if (j < PPW - 1) {
            const float4* np = ep_base + (size_t)(p + 1) * (NCH * NCH / 4);
#pragma unroll
            for (int k = 0; k < 16; ++k) en[k] = np[k * 64];
        }

        const float4 x4 = *reinterpret_cast<const float4*>(&xt[jj][4 * s]);

        float acc[16];
#pragma unroll
        for (int k = 0; k < 16; ++k) {
            float4 w4 = Wl[k * 64 + lane];   // contiguous b128, conflict-free
            float wx0 = w4.x * x4.x, wx1 = w4.y * x4.y;
            float wx2 = w4.z * x4.z, wx3 = w4.w * x4.w;
            float f0 = fmaf(0.1f, e[k].x, 1.0f);
            float f1 = fmaf(0.1f, e[k].y, 1.0f);
            float f2 = fmaf(0.1f, e[k].z, 1.0f);
            float f3 = fmaf(0.1f, e[k].w, 1.0f);
            float a  = wx0 * f0;
            a = fmaf(wx1, f1, a);
            a = fmaf(wx2, f2, a);
            a = fmaf(wx3, f3, a);
            acc[k] = a;
        }

        // Reduce-scatter over lane bits 0..3 (15 shuffles); lane l ends with
        // the finished sum for o = 4*(l&15)+(l>>4).
        float r8[8];
#pragma unroll
        for (int t = 0; t < 8; ++t) {
            float mine  = (s & 8) ? acc[t + 8] : acc[t];
            float other = (s & 8) ? acc[t]     : acc[t + 8];
            r8[t] = mine + __shfl_xor(other, 8, 64);
        }
        float r4[4];
#pragma unroll
        for (int t = 0; t < 4; ++t) {
            float mine  = (s & 4) ? r8[t + 4] : r8[t];
            float other = (s & 4) ? r8[t]     : r8[t + 4];
            r4[t] = mine + __shfl_xor(other, 4, 64);
        }
        float r2[2];
#pragma unroll
        for (int t = 0; t < 2; ++t) {
            float mine  = (s & 2) ? r4[t + 2] : r4[t];
            float other = (s & 2) ? r4[t]     : r4[t + 2];
            r2[t] = mine + __shfl_xor(other, 2, 64);
        }
        {
            float mine  = (s & 1) ? r2[1] : r2[0];
            float other = (s & 1) ? r2[0] : r2[1];
            float y = mine + __shfl_xor(other, 1, 64) + b_fin;
            out[(size_t)o_fin * P_TOTAL + p] = y;
        }

        if (j < PPW - 1) {
#pragma unroll
            for (int k = 0; k < 16; ++k) e[k] = en[k];
        }
    }
}

extern "C" void kernel_launch(void* const* d_in, const int* in_sizes, int n_in,
                              void* d_out, int out_size, void* d_ws, size_t ws_size,
                              hipStream_t stream) {
    const float* x    = (const float*)d_in[0];  // [64, 32768]
    const float* W    = (const float*)d_in[1];  // [64,64]
    const float* bias = (const float*)d_in[2];  // [64]
    const float* eps  = (const float*)d_in[3];  // [32768,64,64]
    float* out        = (float*)d_out;          // [64, 32768]

    dim3 grid(P_TOTAL / PPB);   // 1024 blocks
    dim3 block(256);
    noise_conv_kernel<<<grid, block, 0, stream>>>(x, W, bias, eps, out);
}